// Round 1
// baseline (484.214 us; speedup 1.0000x reference)
//
#include <hip/hip_runtime.h>
#include <hip/hip_bf16.h>
#include <cstdint>
#include <cstddef>

typedef __attribute__((ext_vector_type(4))) float f32x4;
typedef __attribute__((ext_vector_type(8))) short short8;
typedef unsigned short ushort_t;

// ---- helpers ---------------------------------------------------------------
__device__ __forceinline__ ushort_t f2bf(float f) {
  unsigned u = __builtin_bit_cast(unsigned, f);
  u = u + 0x7FFFu + ((u >> 16) & 1u);          // round-to-nearest-even
  return (ushort_t)(u >> 16);
}
__device__ __forceinline__ float bf2f(ushort_t s) {
  unsigned u = ((unsigned)s) << 16;
  return __builtin_bit_cast(float, u);
}
__device__ __forceinline__ void load_lds16(const void* g, void* l) {
  __builtin_amdgcn_global_load_lds((const __attribute__((address_space(1))) void*)g,
                                   (__attribute__((address_space(3))) void*)l, 16, 0, 0);
}

// LDS byte-offset swizzles (applied identically on write and read)
__device__ __forceinline__ int swzA(int row, int b) { return row*128 + (b ^ ((row & 7) << 4)); }   // 128B rows (As/Bs)
__device__ __forceinline__ int swzQ(int row, int b) { return row*64  + (b ^ (((row >> 1) & 3) << 4)); } // 64B rows (qs/ks)
__device__ __forceinline__ int swzV(int d,   int b) { return d*256   + (b ^ ((d & 7) << 4)); }     // 256B rows (vt)
__device__ __forceinline__ int swzP(int row, int b) { return row*128 + (b ^ ((row & 7) << 4)); }   // 128B rows (ps)

// ---- kernel 1: hidden f32 -> bf16 ------------------------------------------
__global__ __launch_bounds__(256) void k_cvt_bf16(const float4* __restrict__ in,
                                                  ushort_t* __restrict__ outp, int n4) {
  int i = blockIdx.x * 256 + threadIdx.x;
  int stride = gridDim.x * 256;
  for (; i < n4; i += stride) {
    float4 v = in[i];
    ushort4 o = { f2bf(v.x), f2bf(v.y), f2bf(v.z), f2bf(v.w) };
    *(ushort4*)(outp + (size_t)i * 4) = o;
  }
}

// ---- kernel 2: build head-grouped Wcat (bf16) + bcat (f32) -----------------
// Column order per head h: [q rows h*32..+32 | k rows | v rows]  (1536 rows of K=512)
__global__ __launch_bounds__(256) void k_wcat(const float* __restrict__ qw, const float* __restrict__ qb,
                                              const float* __restrict__ kw, const float* __restrict__ vw,
                                              const float* __restrict__ vb,
                                              ushort_t* __restrict__ Wcat, float* __restrict__ bcat) {
  int o = blockIdx.x;                   // 0..1535
  int h = o / 96, r = o % 96;
  const float* src; float bias;
  if (r < 32)      { src = qw + (size_t)(h*32 + r)      * 512; bias = qb[h*32 + r]; }
  else if (r < 64) { src = kw + (size_t)(h*32 + r - 32) * 512; bias = 0.f; }
  else             { src = vw + (size_t)(h*32 + r - 64) * 512; bias = vb[h*32 + r - 64]; }
  int t = threadIdx.x;
  Wcat[(size_t)o*512 + t]       = f2bf(src[t]);
  Wcat[(size_t)o*512 + t + 256] = f2bf(src[t + 256]);
  if (t == 0) bcat[o] = bias;
}

// ---- kernel 3: CPB MLP -> bias16[t][h] = 16*sigmoid(hbias) -----------------
__global__ __launch_bounds__(256) void k_bias(const float* __restrict__ w1, const float* __restrict__ b1,
                                              const float* __restrict__ w2, float* __restrict__ bias16) {
  int t = blockIdx.x;                   // 0..224 table rows
  int a = t / 15, b = t % 15;
  float x = (float)(a - 7) * (8.f / 7.f);
  float y = (float)(b - 7) * (8.f / 7.f);
  float fx = (x == 0.f) ? 0.f : copysignf(log2f(fabsf(x) + 1.f) * (1.f / 3.f), x);
  float fy = (y == 0.f) ? 0.f : copysignf(log2f(fabsf(y) + 1.f) * (1.f / 3.f), y);
  int wv = threadIdx.x >> 6, lane = threadIdx.x & 63;
  float acc[4] = {0.f, 0.f, 0.f, 0.f};
  for (int it = 0; it < 8; ++it) {
    int j = it*64 + lane;
    float act = fmaxf(fx * w1[2*j] + fy * w1[2*j + 1] + b1[j], 0.f);
#pragma unroll
    for (int hh = 0; hh < 4; ++hh)
      acc[hh] += act * w2[(wv*4 + hh)*512 + j];
  }
#pragma unroll
  for (int hh = 0; hh < 4; ++hh) {
    float v = acc[hh];
    for (int s = 1; s < 64; s <<= 1) v += __shfl_xor(v, s);
    if (lane == 0) bias16[t*16 + wv*4 + hh] = 16.f / (1.f + __expf(-v));
  }
}

// ---- kernel 4: fused QKV projection + cosine window attention --------------
// block = (mtile, head): 128 hidden rows (= windows 2m, 2m+1) x 96 cols (q|k|v of head h)
#define AS_OFF 0          // 16 KiB  [128][64] bf16   (GEMM phase)
#define BS_OFF 16384      // 12 KiB  [96][64]  bf16   (GEMM phase)
#define QS_OFF 0          //  8 KiB  [128][32] bf16   (attn phase, aliases As)
#define KS_OFF 8192       //  8 KiB  [128][32] bf16
#define VT_OFF 16384      //  8 KiB  [32][128] bf16 (V transposed)
#define PS_OFF 24576      //  8 KiB  [64][64]  bf16 (P, per window)

__global__ __launch_bounds__(256) void k_main(const ushort_t* __restrict__ hbf,
                                              const ushort_t* __restrict__ Wcat,
                                              const float* __restrict__ bcat,
                                              const float* __restrict__ bias16,
                                              const float* __restrict__ lscale,
                                              float* __restrict__ out) {
  __shared__ __align__(128) char lb_raw[32768];
  char* lb = lb_raw;

  int bid = blockIdx.x;
  int wg = (bid & 7) * 2048 + (bid >> 3);      // bijective XCD swizzle (16384 % 8 == 0)
  int mtile = wg >> 4;                         // 0..1023
  int h     = wg & 15;

  int tid = threadIdx.x;
  int w = tid >> 6, lane = tid & 63;
  int lm = lane & 15, lg = lane >> 4;

  const ushort_t* Ag = hbf  + (size_t)mtile * 128 * 512;
  const ushort_t* Wg = Wcat + (size_t)h * 96 * 512;

  f32x4 acc[2][6] = {};

  // ---- GEMM: 128x96 += A(128x512) * Wg^T, BK=64, m97 2-barrier structure ----
  for (int ks = 0; ks < 8; ++ks) {
    int k0 = ks * 64;
#pragma unroll
    for (int i = 0; i < 4; ++i) {              // stage A: 16 KiB
      int lo  = i*4096 + w*1024;
      int row = (lo >> 7) + (lane >> 3);
      int sl  = (lane & 7) ^ (row & 7);        // inverse-swizzled source slot
      load_lds16(Ag + (size_t)row*512 + k0 + sl*8, lb + AS_OFF + lo);
    }
#pragma unroll
    for (int i = 0; i < 3; ++i) {              // stage B: 12 KiB
      int lo  = i*4096 + w*1024;
      int row = (lo >> 7) + (lane >> 3);
      int sl  = (lane & 7) ^ (row & 7);
      load_lds16(Wg + (size_t)row*512 + k0 + sl*8, lb + BS_OFF + lo);
    }
    __syncthreads();
#pragma unroll
    for (int ch = 0; ch < 2; ++ch) {
      int bo = ch*64 + lg*16;
      short8 av[2], bv[6];
#pragma unroll
      for (int i = 0; i < 2; ++i) av[i] = *(const short8*)(lb + AS_OFF + swzA(w*32 + i*16 + lm, bo));
#pragma unroll
      for (int j = 0; j < 6; ++j) bv[j] = *(const short8*)(lb + BS_OFF + swzA(j*16 + lm, bo));
#pragma unroll
      for (int i = 0; i < 2; ++i)
#pragma unroll
        for (int j = 0; j < 6; ++j)
          acc[i][j] = __builtin_amdgcn_mfma_f32_16x16x32_bf16(av[i], bv[j], acc[i][j], 0, 0, 0);
    }
    __syncthreads();
  }

  // ---- epilogue: +bias, bf16, scatter to attn LDS tiles (aliases As/Bs) ----
  float bb[6];
#pragma unroll
  for (int j = 0; j < 6; ++j) bb[j] = bcat[h*96 + j*16 + lm];
#pragma unroll
  for (int i = 0; i < 2; ++i) {
#pragma unroll
    for (int j = 0; j < 6; ++j) {
#pragma unroll
      for (int r = 0; r < 4; ++r) {
        float val = acc[i][j][r] + bb[j];
        int row = w*32 + i*16 + lg*4 + r;      // 0..127 (token row within 2 windows)
        ushort_t b16 = f2bf(val);
        if (j < 2)      *(ushort_t*)(lb + QS_OFF + swzQ(row, (j*16 + lm)*2))     = b16;
        else if (j < 4) *(ushort_t*)(lb + KS_OFF + swzQ(row, ((j-2)*16 + lm)*2)) = b16;
        else            *(ushort_t*)(lb + VT_OFF + swzV((j-4)*16 + lm, row*2))   = b16;  // transposed V
      }
    }
  }
  __syncthreads();

  // ---- normalize q (fold in logit scale) and k: one (row,half) per thread --
  {
    int row = tid >> 1, half = tid & 1;
    float scl = __expf(fminf(lscale[h], 4.6051701860f));   // exp(min(ls, ln 100))
#pragma unroll
    for (int qk = 0; qk < 2; ++qk) {
      char* base = lb + (qk ? KS_OFF : QS_OFF);
      int a0 = swzQ(row, half*32), a1 = swzQ(row, half*32 + 16);
      short8 v0 = *(short8*)(base + a0), v1 = *(short8*)(base + a1);
      float f[16]; float ss = 0.f;
#pragma unroll
      for (int e = 0; e < 8; ++e) { f[e]   = bf2f((ushort_t)v0[e]); ss += f[e]*f[e]; }
#pragma unroll
      for (int e = 0; e < 8; ++e) { f[8+e] = bf2f((ushort_t)v1[e]); ss += f[8+e]*f[8+e]; }
      ss += __shfl_xor(ss, 1);                 // partner thread holds other 16 dims
      float rn = rsqrtf(ss) * (qk ? 1.f : scl);
#pragma unroll
      for (int e = 0; e < 8; ++e) v0[e] = (short)f2bf(f[e]   * rn);
#pragma unroll
      for (int e = 0; e < 8; ++e) v1[e] = (short)f2bf(f[8+e] * rn);
      *(short8*)(base + a0) = v0;
      *(short8*)(base + a1) = v1;
    }
  }
  __syncthreads();

  // ---- relative-position bias fragment (identical for both windows) -------
  float bfrag[4][4];
#pragma unroll
  for (int c = 0; c < 4; ++c) {
    int m = c*16 + lm; int rm = m >> 3, cm = m & 7;
#pragma unroll
    for (int r = 0; r < 4; ++r) {
      int n = w*16 + lg*4 + r;
      int idx = ((n >> 3) - rm + 7)*15 + ((n & 7) - cm + 7);
      bfrag[c][r] = bias16[idx*16 + h];
    }
  }

  // ---- attention: wave w owns rows [16w,16w+16) of each window -------------
#pragma unroll
  for (int win = 0; win < 2; ++win) {
    short8 aq = *(const short8*)(lb + QS_OFF + swzQ(win*64 + w*16 + lm, lg*16));
    f32x4 sacc[4];
#pragma unroll
    for (int c = 0; c < 4; ++c) {
      short8 bk = *(const short8*)(lb + KS_OFF + swzQ(win*64 + c*16 + lm, lg*16));
      f32x4 z = {0.f, 0.f, 0.f, 0.f};
      sacc[c] = __builtin_amdgcn_mfma_f32_16x16x32_bf16(aq, bk, z, 0, 0, 0);
    }
    float mx[4], sum[4], rs[4];
#pragma unroll
    for (int r = 0; r < 4; ++r) {
#pragma unroll
      for (int c = 0; c < 4; ++c) sacc[c][r] += bfrag[c][r];
      float v = fmaxf(fmaxf(sacc[0][r], sacc[1][r]), fmaxf(sacc[2][r], sacc[3][r]));
      v = fmaxf(v, __shfl_xor(v, 1)); v = fmaxf(v, __shfl_xor(v, 2));
      v = fmaxf(v, __shfl_xor(v, 4)); v = fmaxf(v, __shfl_xor(v, 8));
      mx[r] = v; sum[r] = 0.f;
    }
#pragma unroll
    for (int c = 0; c < 4; ++c)
#pragma unroll
      for (int r = 0; r < 4; ++r) {
        float p = __expf(sacc[c][r] - mx[r]); sacc[c][r] = p; sum[r] += p;
      }
#pragma unroll
    for (int r = 0; r < 4; ++r) {
      float s = sum[r];
      s += __shfl_xor(s, 1); s += __shfl_xor(s, 2); s += __shfl_xor(s, 4); s += __shfl_xor(s, 8);
      rs[r] = 1.f / s;
    }
    // write P (bf16) — wave-private rows, in-order LDS makes RAW safe
#pragma unroll
    for (int c = 0; c < 4; ++c) {
      int m = c*16 + lm;
#pragma unroll
      for (int r = 0; r < 4; ++r) {
        int n = w*16 + lg*4 + r;
        *(ushort_t*)(lb + PS_OFF + swzP(n, m*2)) = f2bf(sacc[c][r] * rs[r]);
      }
    }
    // PV: O(16x32) = P(16x64) @ V(64x32)
    f32x4 oacc[2] = {};
#pragma unroll
    for (int kk = 0; kk < 2; ++kk) {
      short8 ap = *(const short8*)(lb + PS_OFF + swzP(w*16 + lm, kk*64 + lg*16));
#pragma unroll
      for (int c = 0; c < 2; ++c) {
        short8 bvv = *(const short8*)(lb + VT_OFF + swzV(c*16 + lm, win*128 + kk*64 + lg*16));
        oacc[c] = __builtin_amdgcn_mfma_f32_16x16x32_bf16(ap, bvv, oacc[c], 0, 0, 0);
      }
    }
    size_t gw = (size_t)mtile*2 + win;
#pragma unroll
    for (int c = 0; c < 2; ++c)
#pragma unroll
      for (int r = 0; r < 4; ++r) {
        int n = w*16 + lg*4 + r;
        out[(gw*64 + n)*512 + h*32 + c*16 + lm] = oacc[c][r];
      }
  }
}

// ---- launcher ---------------------------------------------------------------
extern "C" void kernel_launch(void* const* d_in, const int* in_sizes, int n_in,
                              void* d_out, int out_size, void* d_ws, size_t ws_size,
                              hipStream_t stream) {
  (void)in_sizes; (void)n_in; (void)out_size; (void)ws_size;
  const float* hidden = (const float*)d_in[0];
  const float* q_w    = (const float*)d_in[1];
  const float* q_b    = (const float*)d_in[2];
  const float* k_w    = (const float*)d_in[3];
  const float* v_w    = (const float*)d_in[4];
  const float* v_b    = (const float*)d_in[5];
  const float* lscale = (const float*)d_in[6];
  const float* cpb_w1 = (const float*)d_in[7];
  const float* cpb_b1 = (const float*)d_in[8];
  const float* cpb_w2 = (const float*)d_in[9];
  float* out = (float*)d_out;

  char* wsb = (char*)d_ws;
  ushort_t* hbf    = (ushort_t*)wsb;                                  // 134,217,728 B
  ushort_t* Wcat   = (ushort_t*)(wsb + 134217728);                    //   1,572,864 B
  float*    bcat   = (float*)(wsb + 134217728 + 1572864);             //       6,144 B
  float*    bias16 = (float*)(wsb + 134217728 + 1572864 + 6144);      //      14,400 B

  hipLaunchKernelGGL(k_cvt_bf16, dim3(2048), dim3(256), 0, stream,
                     (const float4*)hidden, hbf, 16777216);
  hipLaunchKernelGGL(k_wcat, dim3(1536), dim3(256), 0, stream,
                     q_w, q_b, k_w, v_w, v_b, Wcat, bcat);
  hipLaunchKernelGGL(k_bias, dim3(225), dim3(256), 0, stream,
                     cpb_w1, cpb_b1, cpb_w2, bias16);
  hipLaunchKernelGGL(k_main, dim3(16384), dim3(256), 0, stream,
                     hbf, Wcat, bcat, bias16, lscale, out);
}